// Round 1
// baseline (460.399 us; speedup 1.0000x reference)
//
#include <hip/hip_runtime.h>
#include <hip/hip_bf16.h>

// Problem constants
#define NN 8192
#define FF 128
#define DD 128
#define HH 2
#define ALPHA 0.3f
#define MAXNNZ 1024

// ---------------------------------------------------------------------------
// Kernel A: c1[h,f] = sum_d Wmap[h,f,d]*a1_w[h,d]; c2 likewise with a2_w.
// 256 threads total (H*F).
// ---------------------------------------------------------------------------
__global__ __launch_bounds__(256) void c_kernel(
    const float* __restrict__ Wmap, const float* __restrict__ a1w,
    const float* __restrict__ a2w, float* __restrict__ c1, float* __restrict__ c2) {
  int t = threadIdx.x;              // 0..255
  int h = t >> 7, f = t & 127;
  const float* wrow = Wmap + ((size_t)h * FF + f) * DD;
  const float* a1 = a1w + h * DD;
  const float* a2 = a2w + h * DD;
  float s1 = 0.f, s2 = 0.f;
  #pragma unroll 8
  for (int d = 0; d < DD; d++) {
    float w = wrow[d];
    s1 += w * a1[d];
    s2 += w * a2[d];
  }
  c1[t] = s1;
  c2[t] = s2;
}

// ---------------------------------------------------------------------------
// Kernel B: sa1[h,n] = x[n,:].c1[h,:] + a1_b[h]; sa2 likewise.
// One block (128 threads) per node; 4 simultaneous reductions.
// ---------------------------------------------------------------------------
__global__ __launch_bounds__(128) void sa_kernel(
    const float* __restrict__ x, const float* __restrict__ c1,
    const float* __restrict__ c2, const float* __restrict__ a1b,
    const float* __restrict__ a2b, float* __restrict__ sa1, float* __restrict__ sa2) {
  int n = blockIdx.x;
  int f = threadIdx.x;
  float xv = x[(size_t)n * FF + f];
  float p00 = xv * c1[f];         // head 0, score 1
  float p01 = xv * c1[FF + f];    // head 1, score 1
  float p10 = xv * c2[f];         // head 0, score 2
  float p11 = xv * c2[FF + f];    // head 1, score 2
  #pragma unroll
  for (int o = 32; o > 0; o >>= 1) {
    p00 += __shfl_down(p00, o);
    p01 += __shfl_down(p01, o);
    p10 += __shfl_down(p10, o);
    p11 += __shfl_down(p11, o);
  }
  __shared__ float part[2][4];
  int w = f >> 6;
  if ((f & 63) == 0) {
    part[w][0] = p00; part[w][1] = p01; part[w][2] = p10; part[w][3] = p11;
  }
  __syncthreads();
  if (f == 0) {
    sa1[n]      = part[0][0] + part[1][0] + a1b[0];
    sa1[NN + n] = part[0][1] + part[1][1] + a1b[1];
    sa2[n]      = part[0][2] + part[1][2] + a2b[0];
    sa2[NN + n] = part[0][3] + part[1][3] + a2b[1];
  }
}

// ---------------------------------------------------------------------------
// Kernel C: value[h] = x @ kernel[h]   (8192x128 @ 128x128, fp32)
// Block: 256 threads, 32 rows. B staged in LDS in two 64-row k-phases
// (keeps static LDS <= 64KB). A tile staged with pitch 129 (conflict-free
// broadcast reads). Thread tile: 4 rows x 4 cols (float4).
// ---------------------------------------------------------------------------
__global__ __launch_bounds__(256) void value_gemm(
    const float* __restrict__ x, const float* __restrict__ kern,
    float* __restrict__ value) {
  int h = blockIdx.y;
  int row0 = blockIdx.x * 32;
  __shared__ float Bl[64 * 128];    // 32 KB
  __shared__ float Al[32 * 129];    // 16.5 KB
  const float4* Bg4 = (const float4*)(kern + (size_t)h * FF * DD);
  const float4* Ag4 = (const float4*)(x + (size_t)row0 * FF);
  float4* Bl4 = (float4*)Bl;
  int tid = threadIdx.x;

  // stage A: 32 rows x 128 cols = 1024 float4
  #pragma unroll
  for (int q = 0; q < 4; q++) {
    int idx = q * 256 + tid;        // 0..1023
    int r = idx >> 5, c4 = idx & 31;
    float4 g = Ag4[idx];
    Al[r * 129 + c4 * 4 + 0] = g.x;
    Al[r * 129 + c4 * 4 + 1] = g.y;
    Al[r * 129 + c4 * 4 + 2] = g.z;
    Al[r * 129 + c4 * 4 + 3] = g.w;
  }

  int cg = tid & 31;                // column group: cols cg*4..cg*4+3
  int rg = tid >> 5;                // 0..7; rows rg, rg+8, rg+16, rg+24
  float4 acc[4];
  #pragma unroll
  for (int m = 0; m < 4; m++) acc[m] = make_float4(0.f, 0.f, 0.f, 0.f);

  for (int kp = 0; kp < 2; kp++) {
    __syncthreads();                // protect Bl from previous phase readers
    // stage B rows kp*64 .. kp*64+63 : 2048 float4
    #pragma unroll
    for (int q = 0; q < 8; q++)
      Bl4[q * 256 + tid] = Bg4[kp * 2048 + q * 256 + tid];
    __syncthreads();
    for (int k2 = 0; k2 < 64; k2++) {
      int k = kp * 64 + k2;
      float4 bv = *(const float4*)&Bl[k2 * 128 + cg * 4];
      #pragma unroll
      for (int m = 0; m < 4; m++) {
        float av = Al[(rg + m * 8) * 129 + k];
        acc[m].x += av * bv.x;
        acc[m].y += av * bv.y;
        acc[m].z += av * bv.z;
        acc[m].w += av * bv.w;
      }
    }
  }
  #pragma unroll
  for (int m = 0; m < 4; m++) {
    int r = row0 + rg + m * 8;
    *(float4*)&value[((size_t)h * NN + r) * DD + cg * 4] = acc[m];
  }
}

// ---------------------------------------------------------------------------
// Kernel D: colsum[h,d] = sum_n value[h,n,d]
// ---------------------------------------------------------------------------
__global__ __launch_bounds__(128) void colsum_kernel(
    const float* __restrict__ value, float* __restrict__ colsum) {
  int h = blockIdx.y, chunk = blockIdx.x, d = threadIdx.x;
  const float* v = value + ((size_t)h * NN + (size_t)chunk * 128) * DD;
  float s = 0.f;
  #pragma unroll 4
  for (int r = 0; r < 128; r++) s += v[r * DD + d];
  atomicAdd(&colsum[h * DD + d], s);
}

// ---------------------------------------------------------------------------
// Kernel E: main sparse-attention kernel. One block (256 thr) per row i.
//   Phase A: float4-scan adj row, compact nonzero column indices into LDS.
//   Phase B: t -> (h = t>>7, d = t&127). acc += (e_ij - 1)*value[h,j,d];
//            denom = (N - deg) + sum e.  out = mean over heads.
// ---------------------------------------------------------------------------
__global__ __launch_bounds__(256) void gat_main(
    const float* __restrict__ adj, const float* __restrict__ sa1,
    const float* __restrict__ sa2, const float* __restrict__ value,
    const float* __restrict__ colsum, const float* __restrict__ bias,
    float* __restrict__ out) {
  int i = blockIdx.x;
  __shared__ int idxbuf[MAXNNZ];
  __shared__ int cnt;
  __shared__ float contrib[256];
  int t = threadIdx.x;
  if (t == 0) cnt = 0;
  __syncthreads();

  const float4* arow = (const float4*)(adj + (size_t)i * NN);
  #pragma unroll
  for (int q = 0; q < 8; q++) {
    int f4 = q * 256 + t;           // 0..2047
    float4 a = arow[f4];
    int j0 = f4 * 4;
    if (a.x != 0.f) { int p = atomicAdd(&cnt, 1); if (p < MAXNNZ) idxbuf[p] = j0; }
    if (a.y != 0.f) { int p = atomicAdd(&cnt, 1); if (p < MAXNNZ) idxbuf[p] = j0 + 1; }
    if (a.z != 0.f) { int p = atomicAdd(&cnt, 1); if (p < MAXNNZ) idxbuf[p] = j0 + 2; }
    if (a.w != 0.f) { int p = atomicAdd(&cnt, 1); if (p < MAXNNZ) idxbuf[p] = j0 + 3; }
  }
  __syncthreads();
  int count = min(cnt, MAXNNZ);

  int h = t >> 7, d = t & 127;
  const float* val = value + (size_t)h * NN * DD;
  const float* s2 = sa2 + (size_t)h * NN;
  float s1 = sa1[(size_t)h * NN + i];
  float acc = 0.f, sume = 0.f;
  for (int k = 0; k < count; k++) {
    int j = idxbuf[k];
    float s = s1 + s2[j];
    float l = (s >= 0.f) ? s : ALPHA * s;
    float e = __expf(l);
    sume += e;
    acc += (e - 1.f) * val[(size_t)j * DD + d];
  }
  float denom = (float)(NN - count) + sume;
  float r = (colsum[h * DD + d] + acc) / denom +
            bias[((size_t)h * NN + i) * DD + d];
  contrib[t] = r;
  __syncthreads();
  if (t < 128) out[(size_t)i * DD + t] = 0.5f * (contrib[t] + contrib[t + 128]);
}

// ---------------------------------------------------------------------------
// Launch
// ---------------------------------------------------------------------------
extern "C" void kernel_launch(void* const* d_in, const int* in_sizes, int n_in,
                              void* d_out, int out_size, void* d_ws, size_t ws_size,
                              hipStream_t stream) {
  const float* x    = (const float*)d_in[0];
  const float* adj  = (const float*)d_in[1];
  const float* Wmap = (const float*)d_in[2];
  const float* a1w  = (const float*)d_in[3];
  const float* a1b  = (const float*)d_in[4];
  const float* a2w  = (const float*)d_in[5];
  const float* a2b  = (const float*)d_in[6];
  const float* kern = (const float*)d_in[7];
  const float* bias = (const float*)d_in[8];
  float* out = (float*)d_out;
  float* ws  = (float*)d_ws;

  // workspace layout (floats)
  float* c1     = ws;            // 256
  float* c2     = ws + 256;      // 256
  float* sa1    = ws + 512;      // 16384
  float* sa2    = ws + 16896;    // 16384
  float* colsum = ws + 33280;    // 256
  float* value  = ws + 33536;    // 2*8192*128 = 2097152

  hipMemsetAsync(colsum, 0, HH * DD * sizeof(float), stream);
  c_kernel<<<1, 256, 0, stream>>>(Wmap, a1w, a2w, c1, c2);
  sa_kernel<<<NN, 128, 0, stream>>>(x, c1, c2, a1b, a2b, sa1, sa2);
  value_gemm<<<dim3(NN / 32, HH), 256, 0, stream>>>(x, kern, value);
  colsum_kernel<<<dim3(NN / 128, HH), 128, 0, stream>>>(value, colsum);
  gat_main<<<NN, 256, 0, stream>>>(adj, sa1, sa2, value, colsum, bias, out);
}

// Round 2
// 455.428 us; speedup vs baseline: 1.0109x; 1.0109x over previous
//
#include <hip/hip_runtime.h>
#include <hip/hip_bf16.h>

// Problem constants
#define NN 8192
#define FF 128
#define DD 128
#define HH 2
#define ALPHA 0.3f
#define MAXNNZ 1024

// ---------------------------------------------------------------------------
// Kernel A: c1[h,f] = sum_d Wmap[h,f,d]*a1_w[h,d]; c2 likewise with a2_w.
// 256 threads total (H*F).
// ---------------------------------------------------------------------------
__global__ __launch_bounds__(256) void c_kernel(
    const float* __restrict__ Wmap, const float* __restrict__ a1w,
    const float* __restrict__ a2w, float* __restrict__ c1, float* __restrict__ c2) {
  int t = threadIdx.x;              // 0..255
  int h = t >> 7, f = t & 127;
  const float* wrow = Wmap + ((size_t)h * FF + f) * DD;
  const float* a1 = a1w + h * DD;
  const float* a2 = a2w + h * DD;
  float s1 = 0.f, s2 = 0.f;
  #pragma unroll 8
  for (int d = 0; d < DD; d++) {
    float w = wrow[d];
    s1 += w * a1[d];
    s2 += w * a2[d];
  }
  c1[t] = s1;
  c2[t] = s2;
}

// ---------------------------------------------------------------------------
// Kernel B: sa1[h,n] = x[n,:].c1[h,:] + a1_b[h]; sa2 likewise.
// One block (128 threads) per node; 4 simultaneous reductions.
// ---------------------------------------------------------------------------
__global__ __launch_bounds__(128) void sa_kernel(
    const float* __restrict__ x, const float* __restrict__ c1,
    const float* __restrict__ c2, const float* __restrict__ a1b,
    const float* __restrict__ a2b, float* __restrict__ sa1, float* __restrict__ sa2) {
  int n = blockIdx.x;
  int f = threadIdx.x;
  float xv = x[(size_t)n * FF + f];
  float p00 = xv * c1[f];         // head 0, score 1
  float p01 = xv * c1[FF + f];    // head 1, score 1
  float p10 = xv * c2[f];         // head 0, score 2
  float p11 = xv * c2[FF + f];    // head 1, score 2
  #pragma unroll
  for (int o = 32; o > 0; o >>= 1) {
    p00 += __shfl_down(p00, o);
    p01 += __shfl_down(p01, o);
    p10 += __shfl_down(p10, o);
    p11 += __shfl_down(p11, o);
  }
  __shared__ float part[2][4];
  int w = f >> 6;
  if ((f & 63) == 0) {
    part[w][0] = p00; part[w][1] = p01; part[w][2] = p10; part[w][3] = p11;
  }
  __syncthreads();
  if (f == 0) {
    sa1[n]      = part[0][0] + part[1][0] + a1b[0];
    sa1[NN + n] = part[0][1] + part[1][1] + a1b[1];
    sa2[n]      = part[0][2] + part[1][2] + a2b[0];
    sa2[NN + n] = part[0][3] + part[1][3] + a2b[1];
  }
}

// ---------------------------------------------------------------------------
// Kernel C: value[h] = x @ kernel[h]   (8192x128 @ 128x128, fp32)
// ---------------------------------------------------------------------------
__global__ __launch_bounds__(256) void value_gemm(
    const float* __restrict__ x, const float* __restrict__ kern,
    float* __restrict__ value) {
  int h = blockIdx.y;
  int row0 = blockIdx.x * 32;
  __shared__ float Bl[64 * 128];    // 32 KB
  __shared__ float Al[32 * 129];    // 16.5 KB
  const float4* Bg4 = (const float4*)(kern + (size_t)h * FF * DD);
  const float4* Ag4 = (const float4*)(x + (size_t)row0 * FF);
  float4* Bl4 = (float4*)Bl;
  int tid = threadIdx.x;

  // stage A: 32 rows x 128 cols = 1024 float4
  #pragma unroll
  for (int q = 0; q < 4; q++) {
    int idx = q * 256 + tid;        // 0..1023
    int r = idx >> 5, c4 = idx & 31;
    float4 g = Ag4[idx];
    Al[r * 129 + c4 * 4 + 0] = g.x;
    Al[r * 129 + c4 * 4 + 1] = g.y;
    Al[r * 129 + c4 * 4 + 2] = g.z;
    Al[r * 129 + c4 * 4 + 3] = g.w;
  }

  int cg = tid & 31;                // column group: cols cg*4..cg*4+3
  int rg = tid >> 5;                // 0..7; rows rg, rg+8, rg+16, rg+24
  float4 acc[4];
  #pragma unroll
  for (int m = 0; m < 4; m++) acc[m] = make_float4(0.f, 0.f, 0.f, 0.f);

  for (int kp = 0; kp < 2; kp++) {
    __syncthreads();
    #pragma unroll
    for (int q = 0; q < 8; q++)
      Bl4[q * 256 + tid] = Bg4[kp * 2048 + q * 256 + tid];
    __syncthreads();
    for (int k2 = 0; k2 < 64; k2++) {
      int k = kp * 64 + k2;
      float4 bv = *(const float4*)&Bl[k2 * 128 + cg * 4];
      #pragma unroll
      for (int m = 0; m < 4; m++) {
        float av = Al[(rg + m * 8) * 129 + k];
        acc[m].x += av * bv.x;
        acc[m].y += av * bv.y;
        acc[m].z += av * bv.z;
        acc[m].w += av * bv.w;
      }
    }
  }
  #pragma unroll
  for (int m = 0; m < 4; m++) {
    int r = row0 + rg + m * 8;
    *(float4*)&value[((size_t)h * NN + r) * DD + cg * 4] = acc[m];
  }
}

// ---------------------------------------------------------------------------
// Kernel D: colsum[h,d] = sum_n value[h,n,d]
// ---------------------------------------------------------------------------
__global__ __launch_bounds__(128) void colsum_kernel(
    const float* __restrict__ value, float* __restrict__ colsum) {
  int h = blockIdx.y, chunk = blockIdx.x, d = threadIdx.x;
  const float* v = value + ((size_t)h * NN + (size_t)chunk * 128) * DD;
  float s = 0.f;
  #pragma unroll 4
  for (int r = 0; r < 128; r++) s += v[r * DD + d];
  atomicAdd(&colsum[h * DD + d], s);
}

// ---------------------------------------------------------------------------
// Kernel E: main sparse-attention kernel. One block (256 thr) per row i.
//   Phase A : float4-scan adj row, compact nonzero column indices into LDS.
//   Phase B1: ONE thread per edge computes em1 = exp(leaky(s)) - 1 for both
//             heads -> LDS; block-reduce sum(em1). denom = N + sum(em1).
//   Phase B2: t -> (h,d). acc += em1[k]*value[h,j,d]; out = mean over heads.
// ---------------------------------------------------------------------------
__global__ __launch_bounds__(256) void gat_main(
    const float* __restrict__ adj, const float* __restrict__ sa1,
    const float* __restrict__ sa2, const float* __restrict__ value,
    const float* __restrict__ colsum, const float* __restrict__ bias,
    float* __restrict__ out) {
  int i = blockIdx.x;
  __shared__ int idxbuf[MAXNNZ];
  __shared__ float em1buf[HH][MAXNNZ];
  __shared__ int cnt;
  __shared__ float sume_sh[HH];
  __shared__ float wred[4][HH];
  __shared__ float contrib[256];
  int t = threadIdx.x;
  if (t == 0) cnt = 0;
  __syncthreads();

  // ---- Phase A: compact adjacency row ----
  const float4* arow = (const float4*)(adj + (size_t)i * NN);
  #pragma unroll
  for (int q = 0; q < 8; q++) {
    int f4 = q * 256 + t;           // 0..2047
    float4 a = arow[f4];
    int j0 = f4 * 4;
    if (a.x != 0.f) { int p = atomicAdd(&cnt, 1); if (p < MAXNNZ) idxbuf[p] = j0; }
    if (a.y != 0.f) { int p = atomicAdd(&cnt, 1); if (p < MAXNNZ) idxbuf[p] = j0 + 1; }
    if (a.z != 0.f) { int p = atomicAdd(&cnt, 1); if (p < MAXNNZ) idxbuf[p] = j0 + 2; }
    if (a.w != 0.f) { int p = atomicAdd(&cnt, 1); if (p < MAXNNZ) idxbuf[p] = j0 + 3; }
  }
  __syncthreads();
  int count = min(cnt, MAXNNZ);

  // ---- Phase B1: per-edge scores (each edge handled by ONE thread) ----
  float s10 = sa1[i];               // head 0 row score
  float s11 = sa1[NN + i];          // head 1 row score
  float l0 = 0.f, l1 = 0.f;         // partial sums of (e-1)
  for (int k = t; k < count; k += 256) {
    int j = idxbuf[k];
    float w0 = s10 + sa2[j];
    float w1 = s11 + sa2[NN + j];
    w0 = (w0 >= 0.f) ? w0 : ALPHA * w0;
    w1 = (w1 >= 0.f) ? w1 : ALPHA * w1;
    float e0 = __expf(w0) - 1.f;
    float e1 = __expf(w1) - 1.f;
    em1buf[0][k] = e0;
    em1buf[1][k] = e1;
    l0 += e0;
    l1 += e1;
  }
  #pragma unroll
  for (int o = 32; o > 0; o >>= 1) {
    l0 += __shfl_down(l0, o);
    l1 += __shfl_down(l1, o);
  }
  int wid = t >> 6;
  if ((t & 63) == 0) { wred[wid][0] = l0; wred[wid][1] = l1; }
  __syncthreads();
  if (t == 0) {
    sume_sh[0] = wred[0][0] + wred[1][0] + wred[2][0] + wred[3][0];
    sume_sh[1] = wred[0][1] + wred[1][1] + wred[2][1] + wred[3][1];
  }
  __syncthreads();

  // ---- Phase B2: weighted gather of value rows ----
  int h = t >> 7, d = t & 127;
  const float* val = value + (size_t)h * NN * DD + d;
  const float* eb = em1buf[h];
  float acc = 0.f;
  #pragma unroll 4
  for (int k = 0; k < count; k++) {
    int j = idxbuf[k];
    acc += eb[k] * val[(size_t)j * DD];
  }
  // denom = (N - count) + sum(e) = N + sum(e-1)
  float denom = (float)NN + sume_sh[h];
  float r = (colsum[h * DD + d] + acc) / denom +
            bias[((size_t)h * NN + i) * DD + d];
  contrib[t] = r;
  __syncthreads();
  if (t < 128) out[(size_t)i * DD + t] = 0.5f * (contrib[t] + contrib[t + 128]);
}

// ---------------------------------------------------------------------------
// Launch
// ---------------------------------------------------------------------------
extern "C" void kernel_launch(void* const* d_in, const int* in_sizes, int n_in,
                              void* d_out, int out_size, void* d_ws, size_t ws_size,
                              hipStream_t stream) {
  const float* x    = (const float*)d_in[0];
  const float* adj  = (const float*)d_in[1];
  const float* Wmap = (const float*)d_in[2];
  const float* a1w  = (const float*)d_in[3];
  const float* a1b  = (const float*)d_in[4];
  const float* a2w  = (const float*)d_in[5];
  const float* a2b  = (const float*)d_in[6];
  const float* kern = (const float*)d_in[7];
  const float* bias = (const float*)d_in[8];
  float* out = (float*)d_out;
  float* ws  = (float*)d_ws;

  // workspace layout (floats)
  float* c1     = ws;            // 256
  float* c2     = ws + 256;      // 256
  float* sa1    = ws + 512;      // 16384
  float* sa2    = ws + 16896;    // 16384
  float* colsum = ws + 33280;    // 256
  float* value  = ws + 33536;    // 2*8192*128 = 2097152

  hipMemsetAsync(colsum, 0, HH * DD * sizeof(float), stream);
  c_kernel<<<1, 256, 0, stream>>>(Wmap, a1w, a2w, c1, c2);
  sa_kernel<<<NN, 128, 0, stream>>>(x, c1, c2, a1b, a2b, sa1, sa2);
  value_gemm<<<dim3(NN / 32, HH), 256, 0, stream>>>(x, kern, value);
  colsum_kernel<<<dim3(NN / 128, HH), 128, 0, stream>>>(value, colsum);
  gat_main<<<NN, 256, 0, stream>>>(adj, sa1, sa2, value, colsum, bias, out);
}